// Round 6
// baseline (165.942 us; speedup 1.0000x reference)
//
#include <hip/hip_runtime.h>
#include <hip/hip_bf16.h>

// Problem constants: S=2048, B=32, He=Hd=1024, A=512, M = S*B = 65536.

typedef float f32x4 __attribute__((ext_vector_type(4)));
typedef __bf16 bf16x8 __attribute__((ext_vector_type(8)));

// workspace layout (bytes)
#define WS_DEC_OFF    0u                               // 32*512*4       = 65536
#define WS_WIMG_OFF   65536u                           // 32 chunks * 32KB = 1048576
#define WS_SCORES_OFF (65536u + 1048576u)              // 32*2048*4      = 262144
#define WS_PART_OFF   (65536u + 1048576u + 262144u)    // 16*32*1024*4   = 2097152

#define WAITLGKM0() asm volatile("s_waitcnt lgkmcnt(0)" ::: "memory")
#define SBAR()      asm volatile("s_barrier" ::: "memory")

// ---------------------------------------------------------------------------
// dec_att[b][a] = dot(dec_out[b,:], W_dec[a,:])   (32 x 512, K=1024)
__global__ void dec_att_kernel(const float* __restrict__ dec_out,
                               const float* __restrict__ W_dec,
                               float* __restrict__ out) {
  int gtid = blockIdx.x * blockDim.x + threadIdx.x;
  int w = gtid >> 6;
  int lane = gtid & 63;
  int b = w >> 9;          // 0..31
  int a = w & 511;         // 0..511
  const float4* dp = (const float4*)(dec_out + b * 1024);
  const float4* wp = (const float4*)(W_dec + a * 1024);
  float sum = 0.f;
#pragma unroll
  for (int i = 0; i < 4; ++i) {
    float4 x = dp[lane + i * 64];
    float4 y = wp[lane + i * 64];
    sum += x.x * y.x + x.y * y.y + x.z * y.z + x.w * y.w;
  }
#pragma unroll
  for (int m = 32; m; m >>= 1) sum += __shfl_xor(sum, m, 64);
  if (lane == 0) out[b * 512 + a] = sum;
}

// ---------------------------------------------------------------------------
// Pre-convert W_enc (512x1024 f32) into 32 K-chunk images, chunk kc =
// [512 rows][32 bf16] row-major (32 KB). The GEMM reads B fragments straight
// from this image (L2-resident) into registers.
__global__ void convert_wenc(const float* __restrict__ W, __bf16* __restrict__ out) {
  int idx = blockIdx.x * 256 + threadIdx.x;   // < 524288
  int kc = idx >> 14;
  int row = (idx >> 5) & 511;
  int j = idx & 31;
  out[idx] = (__bf16)W[row * 1024 + kc * 32 + j];
}

// ---------------------------------------------------------------------------
// One K-step of the scores GEMM, parity CUR (reads A buf CUR, writes buf CUR^1).
// anr = A(t+1) regs (loaded one step ago, HBM latency covered);
// anw <- A(t+2) issued here. B(t+1) -> bnxt issued here (L2, covered by MFMA).
template <int CUR>
__device__ __forceinline__ void gemm_step(
    int t, char* smem, const float* asrc, const char* bptr,
    const int* a_roff, int a_woff,
    bf16x8* bcur, bf16x8* bnxt,
    float4& anw0, float4& anw1, const float4& anr0, const float4& anr1,
    f32x4 acc[4][8]) {
  // issue B(t+1) -> bnxt
  {
    const int tb = (t + 1 > 31) ? 31 : t + 1;
    const char* bs = bptr + (size_t)tb * 32768;
#pragma unroll
    for (int nf = 0; nf < 8; ++nf)
      bnxt[nf] = *(const bf16x8*)(bs + nf * 1024);
  }
  // issue A(t+2) -> anw
  {
    const int ta = (t + 2 > 31) ? 31 : t + 2;
    const float4* as4 = (const float4*)(asrc + ta * 32);
    anw0 = as4[0]; anw1 = as4[1];
  }
  // cvt + ds_write A(t+1) into buf CUR^1 (data one step old; write drains
  // during the MFMA cluster below)
  {
    bf16x8 v;
    v[0] = (__bf16)anr0.x; v[1] = (__bf16)anr0.y;
    v[2] = (__bf16)anr0.z; v[3] = (__bf16)anr0.w;
    v[4] = (__bf16)anr1.x; v[5] = (__bf16)anr1.y;
    v[6] = (__bf16)anr1.z; v[7] = (__bf16)anr1.w;
    *(bf16x8*)(smem + (CUR ^ 1) * 4096 + a_woff) = v;
  }
  // A frags (buf CUR) + MFMA(t)
  {
    char* ab = smem + CUR * 4096;
    bf16x8 af[4];
#pragma unroll
    for (int mf = 0; mf < 4; ++mf) af[mf] = *(const bf16x8*)(ab + a_roff[mf]);
    __builtin_amdgcn_s_setprio(1);
#pragma unroll
    for (int mf = 0; mf < 4; ++mf)
#pragma unroll
      for (int nf = 0; nf < 8; ++nf)
        acc[mf][nf] = __builtin_amdgcn_mfma_f32_16x16x32_bf16(af[mf], bcur[nf],
                                                              acc[mf][nf], 0, 0, 0);
    __builtin_amdgcn_s_setprio(0);
  }
#pragma unroll
  for (int nf = 0; nf < 8; ++nf) bcur[nf] = bnxt[nf];
  WAITLGKM0();
  SBAR();
}

// ---------------------------------------------------------------------------
// Main fused kernel: per 64-row tile of (S*B) compute full-width (A=512)
// enc_att via bf16 MFMA, epilogue scores = sum_a tanh(acc+dec_att)*att_v.
// 4 waves (1M x 4N), wave tile 64x128, 16x16x32 MFMA, K=1024 in BK=32 steps.
// B: global(L2)->VGPR, 1-step prefetch. A: LDS dbuf 2x4KB, rotate-swizzled,
// 2-step register prefetch (HBM latency fully covered). 1 barrier / K-step.
__global__ __launch_bounds__(256, 2) void scores_gemm(
    const float* __restrict__ enc,        // (65536, 1024) f32
    const __bf16* __restrict__ wimg,      // 32 chunks of [512][32] bf16
    const float* __restrict__ dec_att,    // [32][512] f32
    const float* __restrict__ attv,       // [512] f32
    float* __restrict__ scores) {         // [32][2048] f32
  __shared__ __align__(16) char smem[8192];   // A dbuf 2x4KB
  float (*part)[4] = (float(*)[4])smem;       // reused after final barrier

  const int tid = threadIdx.x;
  const int lane = tid & 63;
  const int wc = tid >> 6;      // wave id 0..3 = N quarter
  const int q = lane >> 4;      // 0..3 (k-slot)
  const int c0 = lane & 15;
  const int bm = blockIdx.x;    // 1024 tiles of 64 rows

  f32x4 acc[4][8];
#pragma unroll
  for (int i = 0; i < 4; ++i)
#pragma unroll
    for (int j = 0; j < 8; ++j) acc[i][j] = (f32x4){0.f, 0.f, 0.f, 0.f};

  // ---- A staging: thread stages row = tid>>2, sq = tid&3 (8 f32 -> bf16x8)
  const int srow = tid >> 2;
  const int sq = tid & 3;
  const float* asrc = enc + (size_t)(bm * 64 + srow) * 1024 + sq * 8;
  // rotate-swizzled write offset: row*64 + ((sq + row>>1)&3)*16
  const int a_woff = srow * 64 + (((sq + (srow >> 1)) & 3) << 4);
  // swizzled frag-read offsets: row = mf*16+c0
  int a_roff[4];
#pragma unroll
  for (int mf = 0; mf < 4; ++mf) {
    const int row = mf * 16 + c0;
    a_roff[mf] = row * 64 + (((q + (row >> 1)) & 3) << 4);
  }

  // ---- B pointer: lane's slice of the chunk image; frag nf at +nf*1024B,
  // chunk t at +t*32768B. (row=(wc*128+nf*16+c0), byte = row*64 + q*16)
  const char* bptr = (const char*)wimg + (wc * 128 + c0) * 64 + q * 16;

  bf16x8 bcur[8], bnxt[8];
  float4 anP0, anP1, anQ0, anQ1;   // 2-deep A prefetch slots (named: no scratch)

  // ---- prologue: B(0)->regs, A(0)->LDS buf0, A(1)->anQ
  {
    const float4* as4 = (const float4*)asrc;
    float4 x = as4[0], y = as4[1];       // A(0)
#pragma unroll
    for (int nf = 0; nf < 8; ++nf)
      bcur[nf] = *(const bf16x8*)(bptr + nf * 1024);
    anQ0 = as4[8]; anQ1 = as4[9];        // A(1)  (+32 floats)
    bf16x8 v;
    v[0] = (__bf16)x.x; v[1] = (__bf16)x.y; v[2] = (__bf16)x.z; v[3] = (__bf16)x.w;
    v[4] = (__bf16)y.x; v[5] = (__bf16)y.y; v[6] = (__bf16)y.z; v[7] = (__bf16)y.w;
    *(bf16x8*)(smem + a_woff) = v;
  }
  __syncthreads();

  // ---- main loop: 16 x (even, odd) steps, one barrier per K-step
  for (int tt = 0; tt < 16; ++tt) {
    const int t = tt * 2;
    gemm_step<0>(t,     smem, asrc, bptr, a_roff, a_woff, bcur, bnxt,
                 anP0, anP1, anQ0, anQ1, acc);
    gemm_step<1>(t + 1, smem, asrc, bptr, a_roff, a_woff, bcur, bnxt,
                 anQ0, anQ1, anP0, anP1, acc);
  }

  // ---- epilogue: C/D layout col = lane&15, row = q*4 + reg
  float av[8];
#pragma unroll
  for (int nf = 0; nf < 8; ++nf) av[nf] = attv[wc * 128 + nf * 16 + c0];

#pragma unroll
  for (int mf = 0; mf < 4; ++mf) {
#pragma unroll
    for (int rg = 0; rg < 4; ++rg) {
      const int rl = mf * 16 + q * 4 + rg;             // local row 0..63
      const int b = rl & 31;                           // r = s*32+b, tile%32==0
      const float* drow = dec_att + b * 512 + wc * 128 + c0;
      float sum = 0.f;
#pragma unroll
      for (int nf = 0; nf < 8; ++nf) {
        float x = acc[mf][nf][rg] + drow[nf * 16];
        float e = __expf(2.f * x);                     // tanh(x) = 1 - 2/(e^{2x}+1)
        float t = 1.f - 2.f / (e + 1.f);
        sum += t * av[nf];
      }
      sum += __shfl_xor(sum, 1, 64);
      sum += __shfl_xor(sum, 2, 64);
      sum += __shfl_xor(sum, 4, 64);
      sum += __shfl_xor(sum, 8, 64);
      if (c0 == 0) part[rl][wc] = sum;
    }
  }
  __syncthreads();
  if (tid < 64) {
    float tot = part[tid][0] + part[tid][1] + part[tid][2] + part[tid][3];
    int r = bm * 64 + tid;
    scores[(r & 31) * 2048 + (r >> 5)] = tot;          // scores[b][s]
  }
}

// ---------------------------------------------------------------------------
// softmax over S=2048 per batch row; 32 blocks x 256 threads
__global__ void softmax_kernel(const float* __restrict__ scores,
                               float* __restrict__ weights) {
  const int b = blockIdx.x;
  const int t = threadIdx.x;
  const float4* row = (const float4*)(scores + b * 2048);
  float4 v0 = row[t];
  float4 v1 = row[t + 256];
  float m = fmaxf(fmaxf(fmaxf(v0.x, v0.y), fmaxf(v0.z, v0.w)),
                  fmaxf(fmaxf(v1.x, v1.y), fmaxf(v1.z, v1.w)));
#pragma unroll
  for (int s = 32; s; s >>= 1) m = fmaxf(m, __shfl_xor(m, s, 64));
  __shared__ float redm[4], reds[4];
  if ((t & 63) == 0) redm[t >> 6] = m;
  __syncthreads();
  m = fmaxf(fmaxf(redm[0], redm[1]), fmaxf(redm[2], redm[3]));
  float4 e0, e1;
  e0.x = __expf(v0.x - m); e0.y = __expf(v0.y - m);
  e0.z = __expf(v0.z - m); e0.w = __expf(v0.w - m);
  e1.x = __expf(v1.x - m); e1.y = __expf(v1.y - m);
  e1.z = __expf(v1.z - m); e1.w = __expf(v1.w - m);
  float s8 = e0.x + e0.y + e0.z + e0.w + e1.x + e1.y + e1.z + e1.w;
#pragma unroll
  for (int s = 32; s; s >>= 1) s8 += __shfl_xor(s8, s, 64);
  if ((t & 63) == 0) reds[t >> 6] = s8;
  __syncthreads();
  float inv = 1.f / (reds[0] + reds[1] + reds[2] + reds[3]);
  e0.x *= inv; e0.y *= inv; e0.z *= inv; e0.w *= inv;
  e1.x *= inv; e1.y *= inv; e1.z *= inv; e1.w *= inv;
  float4* wrow = (float4*)(weights + b * 2048);
  wrow[t] = e0;
  wrow[t + 256] = e1;
}

// ---------------------------------------------------------------------------
// context partials: block = (b, s-chunk of 128); thread owns float4 at h=t*4
__global__ void ctx_partial(const float* __restrict__ enc,
                            const float* __restrict__ weights,
                            float* __restrict__ part) {
  const int b = blockIdx.x & 31;
  const int sc = blockIdx.x >> 5;       // 0..15
  const int t = threadIdx.x;
  const float* wrow = weights + b * 2048 + sc * 128;
  const char* ebase = (const char*)(enc + ((size_t)(sc * 128) * 32 + b) * 1024) + t * 16;
  float4 acc = {0.f, 0.f, 0.f, 0.f};
#pragma unroll 4
  for (int i = 0; i < 128; ++i) {
    float4 e = *(const float4*)(ebase + (size_t)i * 131072);
    float ws = wrow[i];
    acc.x += ws * e.x; acc.y += ws * e.y; acc.z += ws * e.z; acc.w += ws * e.w;
  }
  *(float4*)(part + (size_t)(sc * 32 + b) * 1024 + t * 4) = acc;
}

__global__ void ctx_reduce(const float* __restrict__ part, float* __restrict__ ctx) {
  int idx = blockIdx.x * 256 + threadIdx.x;   // < 32768
  float s = 0.f;
#pragma unroll
  for (int c = 0; c < 16; ++c) s += part[c * 32768 + idx];
  ctx[idx] = s;
}

// ---------------------------------------------------------------------------
extern "C" void kernel_launch(void* const* d_in, const int* in_sizes, int n_in,
                              void* d_out, int out_size, void* d_ws, size_t ws_size,
                              hipStream_t stream) {
  const float* dec_out  = (const float*)d_in[0];   // (32, 1024)
  const float* enc_outs = (const float*)d_in[1];   // (2048, 32, 1024)
  const float* W_enc    = (const float*)d_in[2];   // (512, 1024)
  const float* W_dec    = (const float*)d_in[3];   // (512, 1024)
  const float* att_v    = (const float*)d_in[4];   // (512,)

  float* out = (float*)d_out;
  float* ctx = out;                 // (32,1024) = 32768 floats
  float* weights = out + 32768;     // (32,2048) = 65536 floats

  char* ws = (char*)d_ws;
  float*  ws_dec    = (float*)(ws + WS_DEC_OFF);
  __bf16* ws_wimg   = (__bf16*)(ws + WS_WIMG_OFF);
  float*  ws_scores = (float*)(ws + WS_SCORES_OFF);
  float*  ws_part   = (float*)(ws + WS_PART_OFF);

  dec_att_kernel<<<4096, 256, 0, stream>>>(dec_out, W_dec, ws_dec);
  convert_wenc<<<2048, 256, 0, stream>>>(W_enc, ws_wimg);
  scores_gemm<<<1024, 256, 0, stream>>>(enc_outs, ws_wimg, ws_dec, att_v, ws_scores);
  softmax_kernel<<<32, 256, 0, stream>>>(ws_scores, weights);
  ctx_partial<<<512, 256, 0, stream>>>(enc_outs, weights, ws_part);
  ctx_reduce<<<128, 256, 0, stream>>>(ws_part, ctx);
}